// Round 8
// baseline (149.773 us; speedup 1.0000x reference)
//
#include <hip/hip_runtime.h>
#include <math.h>

// ClusterisedSelfAttentionNotLearnable — MFMA, R8: B-frags straight from global
// (Bg is fragment-ordered, so per-lane loads are perfectly coalesced and the
// main loop has ZERO barriers), enc transposed in LDS (epilogue = ds_read_b64).
//   out[n,d] = (1/den[n]) * sum_e enc[n,e] * wbar[n,(d,e)]
//   wbar = exp(scores) @ W' : GEMM [N,256]x[256,240pad] bf16 16x16x32
// j padded to 3 d-blocks of 80 (15 tiles of 16); W' pad cols are zero.

#define NCLUST   256
#define M_BLK    128
#define THREADS  256
#define NTILES   15
#define BG_BYTES (NTILES * 8 * 64 * 16)   // 122880
#define ENCT_STRIDE 272                    // bytes per enc COLUMN (128 rows bf16 + 16 pad)

typedef __attribute__((ext_vector_type(8))) short bfrag_t;   // 8 bf16
typedef __attribute__((ext_vector_type(4))) float cfrag_t;   // 4 f32

static __device__ __forceinline__ unsigned int f2bf_u(float f) {
    unsigned int u = __float_as_uint(f);
    u += 0x7fffu + ((u >> 16) & 1u);     // RNE
    return u >> 16;
}
static __device__ __forceinline__ unsigned int f2bf2(float lo, float hi) {
    return f2bf_u(lo) | (f2bf_u(hi) << 16);
}
static __device__ __forceinline__ float bf2f_lo(unsigned int u) {
    return __uint_as_float(u << 16);
}
static __device__ __forceinline__ float bf2f_hi(unsigned int u) {
    return __uint_as_float(u & 0xffff0000u);
}

// Build W' in fragment order: unit u -> (tile=u>>9, ks=(u>>6)&7, lane=u&63),
// lane=(q=lane>>4, ln=lane&15); holds W'[jp=tile*16+ln][c=ks*32+q*8 .. +8].
// W'[jp][c] = (e<72) ? W[(c*3+d)*72+e] : 0, with d=jp/80, e=jp-80d.
__global__ void prep_kernel(const float* __restrict__ W, uint4* __restrict__ Bg) {
    const int u = blockIdx.x * 256 + threadIdx.x;
    if (u >= NTILES * 8 * 64) return;
    const int lane = u & 63, ks = (u >> 6) & 7, tile = u >> 9;
    const int ln = lane & 15, q = lane >> 4;
    const int jp = tile * 16 + ln;
    const int d  = jp / 80;
    const int e  = jp - d * 80;
    const int c0 = ks * 32 + q * 8;
    unsigned int w[4] = {0u, 0u, 0u, 0u};
    if (e < 72) {
#pragma unroll
        for (int i = 0; i < 4; ++i) {
            float f0 = W[((c0 + 2 * i)     * 3 + d) * 72 + e];
            float f1 = W[((c0 + 2 * i + 1) * 3 + d) * 72 + e];
            w[i] = f2bf2(f0, f1);
        }
    }
    Bg[u] = make_uint4(w[0], w[1], w[2], w[3]);
}

__global__ __launch_bounds__(THREADS, 2) void rgb_attn_mfma(
    const float* __restrict__ X,
    const float* __restrict__ cent,
    const void* __restrict__ Bg,
    float* __restrict__ out, int N)
{
    // encT: column-major enc, encT[col e][row pt] bf16 at e*272 + pt*2
    __shared__ __align__(16) unsigned char encT[80 * ENCT_STRIDE];   // 21760
    __shared__ __align__(16) unsigned char ABuf[16384];              // A-frag exchange
    __shared__ float denomL[M_BLK * 2];

    const int tid  = threadIdx.x;
    const int lane = tid & 63;
    const int wv   = tid >> 6;
    const int q    = lane >> 4;
    const int ln   = lane & 15;

    const int pt  = tid & 127;
    const int h   = tid >> 7;
    const int gpt = blockIdx.x * M_BLK + pt;
    const int gp  = (gpt < N) ? gpt : (N - 1);

    float x[6];
#pragma unroll
    for (int k = 0; k < 6; ++k) x[k] = X[gp * 6 + k];

    // zero pad cols e in [72,80): col = 72+(tid>>5), rows (tid&31)*4 .. +3
    {
        const int col = 72 + (tid >> 5), rowg = tid & 31;
        *(uint2*)(encT + col * ENCT_STRIDE + rowg * 8) = make_uint2(0u, 0u);
    }
    // enc (transposed): thread writes cols dd*12+f (sin) / dd*12+6+f (cos), row pt
#pragma unroll
    for (int k = 0; k < 3; ++k) {
        const int dd = 3 * h + k;
        const float xv = x[dd];
        float s0,c0,s1,c1,s2,c2,s3,c3,s4,c4,s5,c5;
        __sincosf(xv *  1.0f, &s0, &c0);
        __sincosf(xv *  2.0f, &s1, &c1);
        __sincosf(xv *  4.0f, &s2, &c2);
        __sincosf(xv *  8.0f, &s3, &c3);
        __sincosf(xv * 16.0f, &s4, &c4);
        __sincosf(xv * 32.0f, &s5, &c5);
        unsigned char* base = encT + pt * 2 + (dd * 12) * ENCT_STRIDE;
        *(unsigned short*)(base + 0 * ENCT_STRIDE)  = (unsigned short)f2bf_u(s0);
        *(unsigned short*)(base + 1 * ENCT_STRIDE)  = (unsigned short)f2bf_u(s1);
        *(unsigned short*)(base + 2 * ENCT_STRIDE)  = (unsigned short)f2bf_u(s2);
        *(unsigned short*)(base + 3 * ENCT_STRIDE)  = (unsigned short)f2bf_u(s3);
        *(unsigned short*)(base + 4 * ENCT_STRIDE)  = (unsigned short)f2bf_u(s4);
        *(unsigned short*)(base + 5 * ENCT_STRIDE)  = (unsigned short)f2bf_u(s5);
        *(unsigned short*)(base + 6 * ENCT_STRIDE)  = (unsigned short)f2bf_u(c0);
        *(unsigned short*)(base + 7 * ENCT_STRIDE)  = (unsigned short)f2bf_u(c1);
        *(unsigned short*)(base + 8 * ENCT_STRIDE)  = (unsigned short)f2bf_u(c2);
        *(unsigned short*)(base + 9 * ENCT_STRIDE)  = (unsigned short)f2bf_u(c3);
        *(unsigned short*)(base + 10 * ENCT_STRIDE) = (unsigned short)f2bf_u(c4);
        *(unsigned short*)(base + 11 * ENCT_STRIDE) = (unsigned short)f2bf_u(c5);
    }

    // ---- attention: 4 phases of 64 clusters; A staged in frag order ----
    bfrag_t afrag[2][8];
    float dpart = 0.0f;
    uint4* AB4 = (uint4*)ABuf;
#pragma unroll
    for (int p = 0; p < 4; ++p) {
        unsigned int pk[16];
#pragma unroll
        for (int i = 0; i < 16; ++i) {
            const int c0 = p * 64 + h * 32 + 2 * i;
            float sa = fmaf(x[0], cent[c0*3+0], fmaf(x[1], cent[c0*3+1], x[2]*cent[c0*3+2]));
            float sb = fmaf(x[0], cent[c0*3+3], fmaf(x[1], cent[c0*3+4], x[2]*cent[c0*3+5]));
            float ea = __expf(sa), eb_ = __expf(sb);
            dpart += ea + eb_;
            pk[i] = f2bf2(ea, eb_);
        }
        const int bu = ((pt >> 4) * 2 + h) * 64 + (pt & 15);
#pragma unroll
        for (int qq = 0; qq < 4; ++qq)
            AB4[bu + qq * 16] = make_uint4(pk[qq*4+0], pk[qq*4+1], pk[qq*4+2], pk[qq*4+3]);
        if (p == 3) denomL[pt * 2 + h] = dpart;
        __syncthreads();
#pragma unroll
        for (int mt = 0; mt < 2; ++mt)
#pragma unroll
            for (int kw = 0; kw < 2; ++kw)
                afrag[mt][2*p+kw] = *(const bfrag_t*)
                    (ABuf + (((2*wv+mt)*2 + kw)*64 + lane)*16);
        __syncthreads();
    }

    // ---- main loop: B frags straight from global, 1-deep prefetch, NO barriers ----
    float part[3][2][4] = {};
    const char* bgp = (const char*)Bg + lane * 16;   // + (t*8+ks)*1024

    bfrag_t bc[8], bn[8];
#pragma unroll
    for (int ks = 0; ks < 8; ++ks)
        bc[ks] = *(const bfrag_t*)(bgp + ks * 1024);

#pragma unroll 1
    for (int t = 0; t < NTILES; ++t) {
        const char* nxt = bgp + (t + 1) * 8192;
        if (t < NTILES - 1) {
#pragma unroll
            for (int ks = 0; ks < 8; ++ks)
                bn[ks] = *(const bfrag_t*)(nxt + ks * 1024);
        }
        cfrag_t a0 = {0.f,0.f,0.f,0.f}, a1 = {0.f,0.f,0.f,0.f};
#pragma unroll
        for (int ks = 0; ks < 8; ++ks) {
            a0 = __builtin_amdgcn_mfma_f32_16x16x32_bf16(afrag[0][ks], bc[ks], a0, 0,0,0);
            a1 = __builtin_amdgcn_mfma_f32_16x16x32_bf16(afrag[1][ks], bc[ks], a1, 0,0,0);
        }
        // epilogue: enc col ebx, rows (2wv+mt)*16+q*4 .. +3  (one b64 per mt)
        const int tm5 = (t >= 10) ? (t - 10) : ((t >= 5) ? (t - 5) : t);
        const int dblk = (t >= 10) ? 2 : ((t >= 5) ? 1 : 0);
        const int ebx = tm5 * 16 + ln;
#pragma unroll
        for (int mt = 0; mt < 2; ++mt) {
            const int row0 = (2*wv + mt)*16 + q*4;
            const uint2 ev = *(const uint2*)(encT + ebx * ENCT_STRIDE + row0 * 2);
            const float e0 = bf2f_lo(ev.x), e1 = bf2f_hi(ev.x);
            const float e2 = bf2f_lo(ev.y), e3 = bf2f_hi(ev.y);
            part[dblk][mt][0] = fmaf((mt ? a1[0] : a0[0]), e0, part[dblk][mt][0]);
            part[dblk][mt][1] = fmaf((mt ? a1[1] : a0[1]), e1, part[dblk][mt][1]);
            part[dblk][mt][2] = fmaf((mt ? a1[2] : a0[2]), e2, part[dblk][mt][2]);
            part[dblk][mt][3] = fmaf((mt ? a1[3] : a0[3]), e3, part[dblk][mt][3]);
        }
#pragma unroll
        for (int ks = 0; ks < 8; ++ks) bc[ks] = bn[ks];
    }

    // ---- reduce across the 16 n-lanes, normalize, write ----
#pragma unroll
    for (int mask = 1; mask <= 8; mask <<= 1)
#pragma unroll
        for (int d = 0; d < 3; ++d)
#pragma unroll
            for (int mt = 0; mt < 2; ++mt)
#pragma unroll
                for (int r = 0; r < 4; ++r)
                    part[d][mt][r] += __shfl_xor(part[d][mt][r], mask, 64);

    if (ln == 0) {
#pragma unroll
        for (int mt = 0; mt < 2; ++mt)
#pragma unroll
            for (int r = 0; r < 4; ++r) {
                const int pm = (2*wv + mt)*16 + q*4 + r;
                const int g  = blockIdx.x * M_BLK + pm;
                if (g < N) {
                    const float inv = 1.0f / (denomL[pm*2] + denomL[pm*2+1]);
                    out[g*3+0] = part[0][mt][r] * inv;
                    out[g*3+1] = part[1][mt][r] * inv;
                    out[g*3+2] = part[2][mt][r] * inv;
                }
            }
    }
}

// ---- fallback (correct, slow) if d_ws too small ----
__global__ __launch_bounds__(256) void rgb_attn_fallback(
    const float* __restrict__ X, const float* __restrict__ W,
    const float* __restrict__ cent, float* __restrict__ out, int N)
{
    const int n = blockIdx.x * 256 + threadIdx.x;
    const bool valid = (n < N);
    float x[6];
#pragma unroll
    for (int k = 0; k < 6; ++k) x[k] = valid ? X[n * 6 + k] : 0.0f;
    float enc[72];
#pragma unroll
    for (int d = 0; d < 6; ++d)
#pragma unroll
        for (int f = 0; f < 6; ++f) {
            float s, c;
            __sincosf(x[d] * (float)(1 << f), &s, &c);
            enc[d*12+f] = s; enc[d*12+6+f] = c;
        }
    float acc0 = 0, acc1 = 0, acc2 = 0, denom = 0;
#pragma unroll 1
    for (int c = 0; c < NCLUST; ++c) {
        float s = fmaf(x[0], cent[c*3], fmaf(x[1], cent[c*3+1], x[2]*cent[c*3+2]));
        float ew = __expf(s);
        const float* w = W + c * 216;
        float d0 = 0, d1 = 0, d2 = 0;
#pragma unroll
        for (int e = 0; e < 72; ++e) {
            float ee = enc[e];
            d0 = fmaf(ee, w[e], d0);
            d1 = fmaf(ee, w[72 + e], d1);
            d2 = fmaf(ee, w[144 + e], d2);
        }
        denom += ew;
        acc0 = fmaf(ew, d0, acc0); acc1 = fmaf(ew, d1, acc1); acc2 = fmaf(ew, d2, acc2);
    }
    if (valid) {
        float inv = 1.0f / denom;
        out[n*3+0] = acc0*inv; out[n*3+1] = acc1*inv; out[n*3+2] = acc2*inv;
    }
}

extern "C" void kernel_launch(void* const* d_in, const int* in_sizes, int n_in,
                              void* d_out, int out_size, void* d_ws, size_t ws_size,
                              hipStream_t stream)
{
    const float* X    = (const float*)d_in[0];   // [N, 6]
    const float* W    = (const float*)d_in[1];   // [768, 72]
    const float* cent = (const float*)d_in[2];   // [256, 3]
    float* out = (float*)d_out;                  // [N, 3]
    const int N = in_sizes[0] / 6;

    if (ws_size >= (size_t)BG_BYTES) {
        uint4* Bg = (uint4*)d_ws;
        prep_kernel<<<(NTILES * 8 * 64 + 255) / 256, 256, 0, stream>>>(W, Bg);
        const int blocks = (N + M_BLK - 1) / M_BLK;
        rgb_attn_mfma<<<blocks, THREADS, 0, stream>>>(X, cent, (const void*)Bg, out, N);
    } else {
        rgb_attn_fallback<<<(N + 255) / 256, 256, 0, stream>>>(X, W, cent, out, N);
    }
}